// Round 1
// baseline (3424.010 us; speedup 1.0000x reference)
//
#include <hip/hip_runtime.h>
#include <math.h>

// ---------------- problem constants ----------------
constexpr int Lc = 4, Bc = 16, Sc = 512, Hc = 768, NHc = 12, FFc = 3072, Dc = 64;
constexpr int MR = Bc * Sc;            // 8192 token rows
constexpr float SCALEc = 0.125f;       // D^-0.5 = 64^-0.5

typedef __attribute__((ext_vector_type(8))) __bf16 bf16x8;
typedef __attribute__((ext_vector_type(4))) __bf16 bf16x4;
typedef __attribute__((ext_vector_type(4))) float  floatx4;

__device__ inline floatx4 mfma16(bf16x8 a, bf16x8 b, floatx4 c) {
    return __builtin_amdgcn_mfma_f32_16x16x32_bf16(a, b, c, 0, 0, 0);
}
__device__ inline float gelu_f(float x) {
    return 0.5f * x * (1.0f + erff(x * 0.70710678118654752f));
}

// ---------------- LayerNorm: one wave per row (H=768 = 64 lanes * 12) ----------
template<bool FINAL>
__global__ __launch_bounds__(256) void ln_k(
    const float* __restrict__ x, const float* __restrict__ g, const float* __restrict__ bt,
    __bf16* __restrict__ yb, float* __restrict__ yf)
{
    const int row  = blockIdx.x * 4 + (threadIdx.x >> 6);
    const int lane = threadIdx.x & 63;
    const int col  = lane * 12;
    const float* xr = x + (size_t)row * Hc + col;
    float v[12];
    *(float4*)(v + 0) = *(const float4*)(xr + 0);
    *(float4*)(v + 4) = *(const float4*)(xr + 4);
    *(float4*)(v + 8) = *(const float4*)(xr + 8);
    float s = 0.f, s2 = 0.f;
#pragma unroll
    for (int j = 0; j < 12; ++j) { s += v[j]; s2 += v[j] * v[j]; }
#pragma unroll
    for (int o = 32; o > 0; o >>= 1) { s += __shfl_xor(s, o); s2 += __shfl_xor(s2, o); }
    const float mean = s * (1.0f / Hc);
    const float inv  = rsqrtf(s2 * (1.0f / Hc) - mean * mean + 1e-5f);
    float gv[12], bv[12];
    *(float4*)(gv + 0) = *(const float4*)(g + col);
    *(float4*)(gv + 4) = *(const float4*)(g + col + 4);
    *(float4*)(gv + 8) = *(const float4*)(g + col + 8);
    *(float4*)(bv + 0) = *(const float4*)(bt + col);
    *(float4*)(bv + 4) = *(const float4*)(bt + col + 4);
    *(float4*)(bv + 8) = *(const float4*)(bt + col + 8);
    if (FINAL) {
        float o[12];
#pragma unroll
        for (int j = 0; j < 12; ++j) o[j] = (v[j] - mean) * inv * gv[j] + bv[j];
        float* yr = yf + (size_t)row * Hc + col;
        *(float4*)(yr + 0) = *(float4*)(o + 0);
        *(float4*)(yr + 4) = *(float4*)(o + 4);
        *(float4*)(yr + 8) = *(float4*)(o + 8);
    } else {
        __bf16 o[12];
#pragma unroll
        for (int j = 0; j < 12; ++j) o[j] = (__bf16)((v[j] - mean) * inv * gv[j] + bv[j]);
        __bf16* yr = yb + (size_t)row * Hc + col;
        *(bf16x4*)(yr + 0) = *(bf16x4*)(o + 0);
        *(bf16x4*)(yr + 4) = *(bf16x4*)(o + 4);
        *(bf16x4*)(yr + 8) = *(bf16x4*)(o + 8);
    }
}

// ---------------- GEMM: C[M,N] = act(A_bf16[M,K] @ W_f32[K,N] + bias) (+resid) ---
// 128x128 tile, BK=32, 4 waves, each wave 64x64 via 4x4 grid of 16x16x32 MFMA.
// ACT: 0=none, 1=exact GELU.  RESID: fp32 out = resid + val, else bf16 out.
template<int ACT, bool RESID>
__global__ __launch_bounds__(256) void gemm_k(
    const __bf16* __restrict__ A, const float* __restrict__ Bw,
    const float* __restrict__ bias, const float* __restrict__ resid,
    float* __restrict__ outF, __bf16* __restrict__ outB,
    int M, int N, int K)
{
    __shared__ __bf16 As[128][40];   // [m][k], +8 pad
    __shared__ __bf16 Bt[128][40];   // [n][k] transposed, +8 pad
    const int tid  = threadIdx.x;
    const int wave = tid >> 6, lane = tid & 63, lhi = lane >> 4, llo = lane & 15;
    const int wm = wave >> 1, wn = wave & 1;
    const int row0 = blockIdx.y * 128, col0 = blockIdx.x * 128;

    floatx4 acc[4][4];
#pragma unroll
    for (int i = 0; i < 4; ++i)
#pragma unroll
        for (int j = 0; j < 4; ++j) acc[i][j] = {0.f, 0.f, 0.f, 0.f};

    for (int kt = 0; kt < K; kt += 32) {
        // stage A: 128x32 bf16, 8-elt vector chunks
#pragma unroll
        for (int c = 0; c < 2; ++c) {
            int id = tid + c * 256;
            int r = id >> 2, c8 = id & 3;
            *(bf16x8*)(&As[r][c8 * 8]) =
                *(const bf16x8*)(A + (size_t)(row0 + r) * K + kt + c8 * 8);
        }
        // stage B: 32x128 fp32 -> bf16 transposed
#pragma unroll
        for (int c = 0; c < 4; ++c) {
            int id = tid + c * 256;
            int r = id >> 5, c4 = id & 31;
            float4 t = *(const float4*)(Bw + (size_t)(kt + r) * N + col0 + c4 * 4);
            Bt[c4 * 4 + 0][r] = (__bf16)t.x;
            Bt[c4 * 4 + 1][r] = (__bf16)t.y;
            Bt[c4 * 4 + 2][r] = (__bf16)t.z;
            Bt[c4 * 4 + 3][r] = (__bf16)t.w;
        }
        __syncthreads();
        bf16x8 af[4], bfr[4];
#pragma unroll
        for (int i = 0; i < 4; ++i)
            af[i] = *(const bf16x8*)(&As[wm * 64 + i * 16 + llo][lhi * 8]);
#pragma unroll
        for (int j = 0; j < 4; ++j)
            bfr[j] = *(const bf16x8*)(&Bt[wn * 64 + j * 16 + llo][lhi * 8]);
#pragma unroll
        for (int i = 0; i < 4; ++i)
#pragma unroll
            for (int j = 0; j < 4; ++j)
                acc[i][j] = mfma16(af[i], bfr[j], acc[i][j]);
        __syncthreads();
    }
    // epilogue: D row=(lane>>4)*4+r, col=lane&15 within each 16x16 block
#pragma unroll
    for (int i = 0; i < 4; ++i) {
#pragma unroll
        for (int j = 0; j < 4; ++j) {
            int colc = col0 + wn * 64 + j * 16 + llo;
            float bb = bias[colc];
#pragma unroll
            for (int r = 0; r < 4; ++r) {
                int rowc = row0 + wm * 64 + i * 16 + lhi * 4 + r;
                float vv = acc[i][j][r] + bb;
                if (ACT == 1) vv = gelu_f(vv);
                size_t idx = (size_t)rowc * N + colc;
                if (RESID) outF[idx] = resid[idx] + vv;
                else       outB[idx] = (__bf16)vv;
            }
        }
    }
}

// ---------------- Flash attention: block = (q-tile of 64, head, batch) ----------
__global__ __launch_bounds__(256) void attn_k(
    const __bf16* __restrict__ q, const __bf16* __restrict__ k,
    const __bf16* __restrict__ v, const float* __restrict__ bias,
    __bf16* __restrict__ o)
{
    __shared__ __bf16 Qs[64][72];
    __shared__ __bf16 Ks[64][72];
    __shared__ __bf16 Vt[64][72];   // [d][t]
    __shared__ __bf16 Ps[64][72];
    __shared__ float  Sf[64][68];
    __shared__ float  mrun[64], lrun[64], alf[64];

    const int qt = blockIdx.x, hh = blockIdx.y, b = blockIdx.z;
    const int tid = threadIdx.x, wave = tid >> 6, lane = tid & 63;
    const int lhi = lane >> 4, llo = lane & 15;
    const size_t base = (size_t)b * Sc * Hc + hh * Dc;

#pragma unroll
    for (int c = 0; c < 2; ++c) {
        int id = tid + c * 256;
        int r = id >> 3, c8 = id & 7;
        *(bf16x8*)(&Qs[r][c8 * 8]) =
            *(const bf16x8*)(q + base + (size_t)(qt * 64 + r) * Hc + c8 * 8);
    }
    if (tid < 64) { mrun[tid] = -1e30f; lrun[tid] = 0.f; }

    floatx4 acco[4];
#pragma unroll
    for (int j = 0; j < 4; ++j) acco[j] = {0.f, 0.f, 0.f, 0.f};

    const float* brow = bias + ((size_t)(b * NHc + hh) * Sc + qt * 64) * Sc;

    for (int kt = 0; kt < Sc; kt += 64) {
        __syncthreads();
        // stage K and V (V transposed)
#pragma unroll
        for (int c = 0; c < 2; ++c) {
            int id = tid + c * 256;
            int r = id >> 3, c8 = id & 7;
            *(bf16x8*)(&Ks[r][c8 * 8]) =
                *(const bf16x8*)(k + base + (size_t)(kt + r) * Hc + c8 * 8);
            bf16x8 vv = *(const bf16x8*)(v + base + (size_t)(kt + r) * Hc + c8 * 8);
#pragma unroll
            for (int jj = 0; jj < 8; ++jj) Vt[c8 * 8 + jj][r] = vv[jj];
        }
        __syncthreads();
        // S = Q K^T   (wave handles 16 q-rows, 64 t-cols)
        floatx4 accs[4];
#pragma unroll
        for (int j = 0; j < 4; ++j) accs[j] = {0.f, 0.f, 0.f, 0.f};
#pragma unroll
        for (int kk = 0; kk < 2; ++kk) {
            bf16x8 aq = *(const bf16x8*)(&Qs[wave * 16 + llo][kk * 32 + lhi * 8]);
#pragma unroll
            for (int nf = 0; nf < 4; ++nf) {
                bf16x8 bk2 = *(const bf16x8*)(&Ks[nf * 16 + llo][kk * 32 + lhi * 8]);
                accs[nf] = mfma16(aq, bk2, accs[nf]);
            }
        }
#pragma unroll
        for (int nf = 0; nf < 4; ++nf) {
#pragma unroll
            for (int r = 0; r < 4; ++r) {
                int lr = wave * 16 + lhi * 4 + r;
                float sv = accs[nf][r] * SCALEc + brow[(size_t)lr * Sc + kt + nf * 16 + llo];
                Sf[lr][nf * 16 + llo] = sv;
            }
        }
        __syncthreads();
        // online softmax: 4 threads per row, 16 cols each
        {
            int row = tid >> 2, seg = tid & 3;
            float sv[16]; float mx = -1e30f;
#pragma unroll
            for (int j2 = 0; j2 < 16; ++j2) { sv[j2] = Sf[row][seg * 16 + j2]; mx = fmaxf(mx, sv[j2]); }
            mx = fmaxf(mx, __shfl_xor(mx, 1));
            mx = fmaxf(mx, __shfl_xor(mx, 2));
            float mold = mrun[row];
            float mnew = fmaxf(mold, mx);
            float al = __expf(mold - mnew);
            float sum = 0.f;
#pragma unroll
            for (int j2 = 0; j2 < 16; ++j2) {
                float p = __expf(sv[j2] - mnew);
                sum += p;
                Ps[row][seg * 16 + j2] = (__bf16)p;
            }
            sum += __shfl_xor(sum, 1);
            sum += __shfl_xor(sum, 2);
            if (seg == 0) { mrun[row] = mnew; lrun[row] = lrun[row] * al + sum; alf[row] = al; }
        }
        __syncthreads();
        // rescale + O += P @ V
#pragma unroll
        for (int nf = 0; nf < 4; ++nf)
#pragma unroll
            for (int r = 0; r < 4; ++r) acco[nf][r] *= alf[wave * 16 + lhi * 4 + r];
#pragma unroll
        for (int kk = 0; kk < 2; ++kk) {
            bf16x8 ap = *(const bf16x8*)(&Ps[wave * 16 + llo][kk * 32 + lhi * 8]);
#pragma unroll
            for (int nf = 0; nf < 4; ++nf) {
                bf16x8 bv2 = *(const bf16x8*)(&Vt[nf * 16 + llo][kk * 32 + lhi * 8]);
                acco[nf] = mfma16(ap, bv2, acco[nf]);
            }
        }
    }
    // epilogue: divide by l, write bf16
#pragma unroll
    for (int nf = 0; nf < 4; ++nf) {
#pragma unroll
        for (int r = 0; r < 4; ++r) {
            int lr = wave * 16 + lhi * 4 + r;
            float oo = acco[nf][r] / lrun[lr];
            o[base + (size_t)(qt * 64 + lr) * Hc + nf * 16 + llo] = (__bf16)oo;
        }
    }
}

// ---------------- orchestration ----------------
extern "C" void kernel_launch(void* const* d_in, const int* in_sizes, int n_in,
                              void* d_out, int out_size, void* d_ws, size_t ws_size,
                              hipStream_t stream)
{
    const float* x     = (const float*)d_in[0];
    const float* abias = (const float*)d_in[1];
    const float* ln1g  = (const float*)d_in[2];
    const float* ln1b  = (const float*)d_in[3];
    const float* wq    = (const float*)d_in[4];
    const float* bq    = (const float*)d_in[5];
    const float* wk    = (const float*)d_in[6];
    const float* bk    = (const float*)d_in[7];
    const float* wv    = (const float*)d_in[8];
    const float* bv    = (const float*)d_in[9];
    const float* wo    = (const float*)d_in[10];
    const float* bo    = (const float*)d_in[11];
    const float* ln2g  = (const float*)d_in[12];
    const float* ln2b  = (const float*)d_in[13];
    const float* w1    = (const float*)d_in[14];
    const float* b1    = (const float*)d_in[15];
    const float* w2    = (const float*)d_in[16];
    const float* b2    = (const float*)d_in[17];
    const float* flng  = (const float*)d_in[18];
    const float* flnb  = (const float*)d_in[19];

    float* h = (float*)d_out;                  // residual stream lives in d_out
    __bf16* y  = (__bf16*)d_ws;                // LN output          [MR,H]
    __bf16* qb = y  + (size_t)MR * Hc;         // Q                  [MR,H]
    __bf16* kb = qb + (size_t)MR * Hc;         // K                  [MR,H]
    __bf16* vb = kb + (size_t)MR * Hc;         // V                  [MR,H]
    __bf16* ob = vb + (size_t)MR * Hc;         // attention out      [MR,H]
    __bf16* fb = ob + (size_t)MR * Hc;         // FFN intermediate   [MR,FF]

    hipMemcpyAsync(h, x, (size_t)MR * Hc * sizeof(float), hipMemcpyDeviceToDevice, stream);

    dim3 blk(256);
    dim3 gLN(MR / 4);
    dim3 gP(Hc / 128, MR / 128);    // (6,64)
    dim3 gF(FFc / 128, MR / 128);   // (24,64)
    dim3 gA(Sc / 64, NHc, Bc);      // (8,12,16)

    for (int l = 0; l < Lc; ++l) {
        const float* wq_l = wq + (size_t)l * Hc * Hc;
        const float* wk_l = wk + (size_t)l * Hc * Hc;
        const float* wv_l = wv + (size_t)l * Hc * Hc;
        const float* wo_l = wo + (size_t)l * Hc * Hc;
        const float* w1_l = w1 + (size_t)l * Hc * FFc;
        const float* w2_l = w2 + (size_t)l * FFc * Hc;

        ln_k<false><<<gLN, blk, 0, stream>>>(h, ln1g + l * Hc, ln1b + l * Hc, y, nullptr);
        gemm_k<0, false><<<gP, blk, 0, stream>>>(y, wq_l, bq + l * Hc, nullptr, nullptr, qb, MR, Hc, Hc);
        gemm_k<0, false><<<gP, blk, 0, stream>>>(y, wk_l, bk + l * Hc, nullptr, nullptr, kb, MR, Hc, Hc);
        gemm_k<0, false><<<gP, blk, 0, stream>>>(y, wv_l, bv + l * Hc, nullptr, nullptr, vb, MR, Hc, Hc);
        attn_k<<<gA, blk, 0, stream>>>(qb, kb, vb, abias, ob);
        gemm_k<0, true><<<gP, blk, 0, stream>>>(ob, wo_l, bo + l * Hc, h, h, nullptr, MR, Hc, Hc);
        ln_k<false><<<gLN, blk, 0, stream>>>(h, ln2g + l * Hc, ln2b + l * Hc, y, nullptr);
        gemm_k<1, false><<<gF, blk, 0, stream>>>(y, w1_l, b1 + l * FFc, nullptr, nullptr, fb, MR, FFc, Hc);
        gemm_k<0, true><<<gP, blk, 0, stream>>>(fb, w2_l, b2 + l * Hc, h, h, nullptr, MR, Hc, FFc);
    }
    ln_k<true><<<gLN, blk, 0, stream>>>(h, flng, flnb, nullptr, h);
}

// Round 2
// 1755.281 us; speedup vs baseline: 1.9507x; 1.9507x over previous
//
#include <hip/hip_runtime.h>
#include <math.h>

// ---------------- problem constants ----------------
constexpr int Lc = 4, Bc = 16, Sc = 512, Hc = 768, NHc = 12, FFc = 3072, Dc = 64;
constexpr int MR = Bc * Sc;            // 8192 token rows
constexpr int QS = 2304;               // fused QKV row stride
constexpr float SCALEc = 0.125f;       // D^-0.5

typedef __attribute__((ext_vector_type(8))) __bf16 bf16x8;
typedef __attribute__((ext_vector_type(4))) __bf16 bf16x4;
typedef __attribute__((ext_vector_type(4))) float  floatx4;

__device__ inline floatx4 mfma16(bf16x8 a, bf16x8 b, floatx4 c) {
    return __builtin_amdgcn_mfma_f32_16x16x32_bf16(a, b, c, 0, 0, 0);
}
__device__ inline float gelu_f(float x) {
    return 0.5f * x * (1.0f + erff(x * 0.70710678118654752f));
}
// async global->LDS, 16B per lane; LDS dest = wave-uniform base + lane*16
__device__ inline void ld16(const __bf16* g, __bf16* l) {
    __builtin_amdgcn_global_load_lds(
        (const __attribute__((address_space(1))) void*)g,
        (__attribute__((address_space(3))) void*)l, 16, 0, 0);
}

// ---------------- LayerNorm: one wave per row ----------
template<bool FINAL>
__global__ __launch_bounds__(256) void ln_k(
    const float* __restrict__ x, const float* __restrict__ g, const float* __restrict__ bt,
    __bf16* __restrict__ yb, float* __restrict__ yf)
{
    const int row  = blockIdx.x * 4 + (threadIdx.x >> 6);
    const int lane = threadIdx.x & 63;
    const int col  = lane * 12;
    const float* xr = x + (size_t)row * Hc + col;
    float v[12];
    *(float4*)(v + 0) = *(const float4*)(xr + 0);
    *(float4*)(v + 4) = *(const float4*)(xr + 4);
    *(float4*)(v + 8) = *(const float4*)(xr + 8);
    float s = 0.f, s2 = 0.f;
#pragma unroll
    for (int j = 0; j < 12; ++j) { s += v[j]; s2 += v[j] * v[j]; }
#pragma unroll
    for (int o = 32; o > 0; o >>= 1) { s += __shfl_xor(s, o); s2 += __shfl_xor(s2, o); }
    const float mean = s * (1.0f / Hc);
    const float inv  = rsqrtf(s2 * (1.0f / Hc) - mean * mean + 1e-5f);
    float gv[12], bv[12];
    *(float4*)(gv + 0) = *(const float4*)(g + col);
    *(float4*)(gv + 4) = *(const float4*)(g + col + 4);
    *(float4*)(gv + 8) = *(const float4*)(g + col + 8);
    *(float4*)(bv + 0) = *(const float4*)(bt + col);
    *(float4*)(bv + 4) = *(const float4*)(bt + col + 4);
    *(float4*)(bv + 8) = *(const float4*)(bt + col + 8);
    if (FINAL) {
        float o[12];
#pragma unroll
        for (int j = 0; j < 12; ++j) o[j] = (v[j] - mean) * inv * gv[j] + bv[j];
        float* yr = yf + (size_t)row * Hc + col;
        *(float4*)(yr + 0) = *(float4*)(o + 0);
        *(float4*)(yr + 4) = *(float4*)(o + 4);
        *(float4*)(yr + 8) = *(float4*)(o + 8);
    } else {
        __bf16 o[12];
#pragma unroll
        for (int j = 0; j < 12; ++j) o[j] = (__bf16)((v[j] - mean) * inv * gv[j] + bv[j]);
        __bf16* yr = yb + (size_t)row * Hc + col;
        *(bf16x4*)(yr + 0) = *(bf16x4*)(o + 0);
        *(bf16x4*)(yr + 4) = *(bf16x4*)(o + 4);
        *(bf16x4*)(yr + 8) = *(bf16x4*)(o + 8);
    }
}

// ---------------- weight transpose+convert: in fp32 [R][C] -> out bf16 [C][R] ---
__global__ __launch_bounds__(256) void transp_k(
    const float* __restrict__ in, __bf16* __restrict__ out, int R, int C)
{
    __shared__ float t[32][33];
    const int c0 = blockIdx.x * 32, r0 = blockIdx.y * 32;
    const int tx = threadIdx.x & 31, ty = threadIdx.x >> 5;   // 32 x 8
#pragma unroll
    for (int i = 0; i < 4; ++i)
        t[ty + i * 8][tx] = in[(size_t)(r0 + ty + i * 8) * C + c0 + tx];
    __syncthreads();
#pragma unroll
    for (int i = 0; i < 4; ++i)
        out[(size_t)(c0 + ty + i * 8) * R + r0 + tx] = (__bf16)t[tx][ty + i * 8];
}

__global__ void bias_cat_k(const float* __restrict__ a, const float* __restrict__ b,
                           const float* __restrict__ c, float* __restrict__ o)
{
    int i = threadIdx.x + blockIdx.x * 256;
    if (i < QS) o[i] = i < Hc ? a[i] : (i < 2 * Hc ? b[i - Hc] : c[i - 2 * Hc]);
}

// ---------------- GEMM: C[M,N] = act(A_bf16[M,K] @ Bt_bf16[N,K]^T + bias) (+resid)
// 128x128 tile, BK=32, 4 waves (2x2), each wave 64x64 via 4x4 16x16x32 MFMA.
// Staging via global_load_lds width-16, unpadded [128][32] LDS (m97 pattern).
template<int ACT, bool RESID>
__global__ __launch_bounds__(256) void gemm2_k(
    const __bf16* __restrict__ A, const __bf16* __restrict__ Bt,
    const float* __restrict__ bias, const float* __restrict__ resid,
    float* __restrict__ outF, __bf16* __restrict__ outB,
    int M, int N, int K)
{
    __shared__ alignas(16) __bf16 As[128 * 32];
    __shared__ alignas(16) __bf16 Bs[128 * 32];
    const int tid  = threadIdx.x;
    const int wave = tid >> 6, lane = tid & 63, lhi = lane >> 4, llo = lane & 15;
    const int wm = wave >> 1, wn = wave & 1;
    const int row0 = blockIdx.y * 128, col0 = blockIdx.x * 128;
    const int srow = lane >> 2;            // 0..15
    const int scol = (lane & 3) * 8;       // 0,8,16,24

    floatx4 acc[4][4];
#pragma unroll
    for (int i = 0; i < 4; ++i)
#pragma unroll
        for (int j = 0; j < 4; ++j) acc[i][j] = {0.f, 0.f, 0.f, 0.f};

    const __bf16* Ab = A  + (size_t)(row0 + wave * 16 + srow) * K + scol;
    const __bf16* Bb = Bt + (size_t)(col0 + wave * 16 + srow) * K + scol;

    for (int kt = 0; kt < K; kt += 32) {
#pragma unroll
        for (int t = 0; t < 2; ++t) {
            ld16(Ab + (size_t)(t * 64) * K + kt, As + (t * 64 + wave * 16) * 32);
            ld16(Bb + (size_t)(t * 64) * K + kt, Bs + (t * 64 + wave * 16) * 32);
        }
        __syncthreads();
        bf16x8 af[4], bfr[4];
#pragma unroll
        for (int i = 0; i < 4; ++i)
            af[i]  = *(const bf16x8*)(As + (wm * 64 + i * 16 + llo) * 32 + lhi * 8);
#pragma unroll
        for (int j = 0; j < 4; ++j)
            bfr[j] = *(const bf16x8*)(Bs + (wn * 64 + j * 16 + llo) * 32 + lhi * 8);
#pragma unroll
        for (int i = 0; i < 4; ++i)
#pragma unroll
            for (int j = 0; j < 4; ++j)
                acc[i][j] = mfma16(af[i], bfr[j], acc[i][j]);
        __syncthreads();
    }
#pragma unroll
    for (int i = 0; i < 4; ++i) {
#pragma unroll
        for (int j = 0; j < 4; ++j) {
            int colc = col0 + wn * 64 + j * 16 + llo;
            float bb = bias[colc];
#pragma unroll
            for (int r = 0; r < 4; ++r) {
                int rowc = row0 + wm * 64 + i * 16 + lhi * 4 + r;
                float vv = acc[i][j][r] + bb;
                if (ACT == 1) vv = gelu_f(vv);
                size_t idx = (size_t)rowc * N + colc;
                if (RESID) outF[idx] = resid[idx] + vv;
                else       outB[idx] = (__bf16)vv;
            }
        }
    }
}

// ---------------- Flash attention: block = (q-tile of 64, head, batch) ----------
// q/k/v read from fused qkv buffer (row stride QS=2304)
__global__ __launch_bounds__(256) void attn_k(
    const __bf16* __restrict__ q, const __bf16* __restrict__ k,
    const __bf16* __restrict__ v, const float* __restrict__ bias,
    __bf16* __restrict__ o)
{
    __shared__ alignas(16) __bf16 Qs[64][72];
    __shared__ alignas(16) __bf16 Ks[64][72];
    __shared__ alignas(16) __bf16 Vt[64][72];   // [d][t]
    __shared__ alignas(16) __bf16 Ps[64][72];
    __shared__ float  Sf[64][68];
    __shared__ float  mrun[64], lrun[64], alf[64];

    const int qt = blockIdx.x, hh = blockIdx.y, b = blockIdx.z;
    const int tid = threadIdx.x, wave = tid >> 6, lane = tid & 63;
    const int lhi = lane >> 4, llo = lane & 15;
    const size_t base  = (size_t)b * Sc * QS + hh * Dc;   // qkv addressing
    const size_t obase = (size_t)b * Sc * Hc + hh * Dc;   // output addressing

#pragma unroll
    for (int c = 0; c < 2; ++c) {
        int id = tid + c * 256;
        int r = id >> 3, c8 = id & 7;
        *(bf16x8*)(&Qs[r][c8 * 8]) =
            *(const bf16x8*)(q + base + (size_t)(qt * 64 + r) * QS + c8 * 8);
    }
    if (tid < 64) { mrun[tid] = -1e30f; lrun[tid] = 0.f; }

    floatx4 acco[4];
#pragma unroll
    for (int j = 0; j < 4; ++j) acco[j] = {0.f, 0.f, 0.f, 0.f};

    const float* brow = bias + ((size_t)(b * NHc + hh) * Sc + qt * 64) * Sc;

    for (int kt = 0; kt < Sc; kt += 64) {
        __syncthreads();
#pragma unroll
        for (int c = 0; c < 2; ++c) {
            int id = tid + c * 256;
            int r = id >> 3, c8 = id & 7;
            *(bf16x8*)(&Ks[r][c8 * 8]) =
                *(const bf16x8*)(k + base + (size_t)(kt + r) * QS + c8 * 8);
            bf16x8 vv = *(const bf16x8*)(v + base + (size_t)(kt + r) * QS + c8 * 8);
#pragma unroll
            for (int jj = 0; jj < 8; ++jj) Vt[c8 * 8 + jj][r] = vv[jj];
        }
        __syncthreads();
        floatx4 accs[4];
#pragma unroll
        for (int j = 0; j < 4; ++j) accs[j] = {0.f, 0.f, 0.f, 0.f};
#pragma unroll
        for (int kk = 0; kk < 2; ++kk) {
            bf16x8 aq = *(const bf16x8*)(&Qs[wave * 16 + llo][kk * 32 + lhi * 8]);
#pragma unroll
            for (int nf = 0; nf < 4; ++nf) {
                bf16x8 bk2 = *(const bf16x8*)(&Ks[nf * 16 + llo][kk * 32 + lhi * 8]);
                accs[nf] = mfma16(aq, bk2, accs[nf]);
            }
        }
#pragma unroll
        for (int nf = 0; nf < 4; ++nf) {
#pragma unroll
            for (int r = 0; r < 4; ++r) {
                int lr = wave * 16 + lhi * 4 + r;
                float sv = accs[nf][r] * SCALEc + brow[(size_t)lr * Sc + kt + nf * 16 + llo];
                Sf[lr][nf * 16 + llo] = sv;
            }
        }
        __syncthreads();
        {
            int row = tid >> 2, seg = tid & 3;
            float sv[16]; float mx = -1e30f;
#pragma unroll
            for (int j2 = 0; j2 < 16; ++j2) { sv[j2] = Sf[row][seg * 16 + j2]; mx = fmaxf(mx, sv[j2]); }
            mx = fmaxf(mx, __shfl_xor(mx, 1));
            mx = fmaxf(mx, __shfl_xor(mx, 2));
            float mold = mrun[row];
            float mnew = fmaxf(mold, mx);
            float al = __expf(mold - mnew);
            float sum = 0.f;
#pragma unroll
            for (int j2 = 0; j2 < 16; ++j2) {
                float p = __expf(sv[j2] - mnew);
                sum += p;
                Ps[row][seg * 16 + j2] = (__bf16)p;
            }
            sum += __shfl_xor(sum, 1);
            sum += __shfl_xor(sum, 2);
            if (seg == 0) { mrun[row] = mnew; lrun[row] = lrun[row] * al + sum; alf[row] = al; }
        }
        __syncthreads();
#pragma unroll
        for (int nf = 0; nf < 4; ++nf)
#pragma unroll
            for (int r = 0; r < 4; ++r) acco[nf][r] *= alf[wave * 16 + lhi * 4 + r];
#pragma unroll
        for (int kk = 0; kk < 2; ++kk) {
            bf16x8 ap = *(const bf16x8*)(&Ps[wave * 16 + llo][kk * 32 + lhi * 8]);
#pragma unroll
            for (int nf = 0; nf < 4; ++nf) {
                bf16x8 bv2 = *(const bf16x8*)(&Vt[nf * 16 + llo][kk * 32 + lhi * 8]);
                acco[nf] = mfma16(ap, bv2, acco[nf]);
            }
        }
    }
#pragma unroll
    for (int nf = 0; nf < 4; ++nf) {
#pragma unroll
        for (int r = 0; r < 4; ++r) {
            int lr = wave * 16 + lhi * 4 + r;
            float oo = acco[nf][r] / lrun[lr];
            o[obase + (size_t)(qt * 64 + lr) * Hc + nf * 16 + llo] = (__bf16)oo;
        }
    }
}

// ---------------- orchestration ----------------
extern "C" void kernel_launch(void* const* d_in, const int* in_sizes, int n_in,
                              void* d_out, int out_size, void* d_ws, size_t ws_size,
                              hipStream_t stream)
{
    const float* x     = (const float*)d_in[0];
    const float* abias = (const float*)d_in[1];
    const float* ln1g  = (const float*)d_in[2];
    const float* ln1b  = (const float*)d_in[3];
    const float* wq    = (const float*)d_in[4];
    const float* bq    = (const float*)d_in[5];
    const float* wk    = (const float*)d_in[6];
    const float* bk    = (const float*)d_in[7];
    const float* wv    = (const float*)d_in[8];
    const float* bv    = (const float*)d_in[9];
    const float* wo    = (const float*)d_in[10];
    const float* bo    = (const float*)d_in[11];
    const float* ln2g  = (const float*)d_in[12];
    const float* ln2b  = (const float*)d_in[13];
    const float* w1    = (const float*)d_in[14];
    const float* b1    = (const float*)d_in[15];
    const float* w2    = (const float*)d_in[16];
    const float* b2    = (const float*)d_in[17];
    const float* flng  = (const float*)d_in[18];
    const float* flnb  = (const float*)d_in[19];

    float* h = (float*)d_out;                       // residual stream
    __bf16* y    = (__bf16*)d_ws;                   // [MR,768]
    __bf16* qkv  = y   + (size_t)MR * Hc;           // [MR,2304]
    __bf16* ob   = qkv + (size_t)MR * QS;           // [MR,768]
    __bf16* fb   = ob  + (size_t)MR * Hc;           // [MR,3072] FFN act
    __bf16* w1t  = fb  + (size_t)MR * FFc;          // [3072,768]
    __bf16* w2t  = w1t + (size_t)FFc * Hc;          // [768,3072]
    float*  bqkv = (float*)(w2t + (size_t)Hc * FFc);// [2304]
    // alias (dead before FFN act is written): QKV + O weights inside fb region
    __bf16* wqkvt = fb;                             // [2304,768]
    __bf16* wot   = fb + (size_t)QS * Hc;           // [768,768]

    hipMemcpyAsync(h, x, (size_t)MR * Hc * sizeof(float), hipMemcpyDeviceToDevice, stream);

    dim3 blk(256);
    dim3 gLN(MR / 4);
    dim3 gQKV(QS / 128, MR / 128);   // (18,64)
    dim3 gP(Hc / 128, MR / 128);     // (6,64)
    dim3 gF(FFc / 128, MR / 128);    // (24,64)
    dim3 gA(Sc / 64, NHc, Bc);       // (8,12,16)
    dim3 gT_HH(Hc / 32, Hc / 32);    // 768x768 transpose
    dim3 gT_HF(FFc / 32, Hc / 32);   // in [768][3072]
    dim3 gT_FH(Hc / 32, FFc / 32);   // in [3072][768]

    for (int l = 0; l < Lc; ++l) {
        const float* wq_l = wq + (size_t)l * Hc * Hc;
        const float* wk_l = wk + (size_t)l * Hc * Hc;
        const float* wv_l = wv + (size_t)l * Hc * Hc;
        const float* wo_l = wo + (size_t)l * Hc * Hc;
        const float* w1_l = w1 + (size_t)l * Hc * FFc;
        const float* w2_l = w2 + (size_t)l * FFc * Hc;

        // weight prep (bf16, transposed to [N][K])
        transp_k<<<gT_HH, blk, 0, stream>>>(wq_l, wqkvt,                        Hc, Hc);
        transp_k<<<gT_HH, blk, 0, stream>>>(wk_l, wqkvt + (size_t)Hc * Hc,      Hc, Hc);
        transp_k<<<gT_HH, blk, 0, stream>>>(wv_l, wqkvt + (size_t)2 * Hc * Hc,  Hc, Hc);
        transp_k<<<gT_HH, blk, 0, stream>>>(wo_l, wot, Hc, Hc);
        transp_k<<<gT_HF, blk, 0, stream>>>(w1_l, w1t, Hc, FFc);
        transp_k<<<gT_FH, blk, 0, stream>>>(w2_l, w2t, FFc, Hc);
        bias_cat_k<<<dim3(9), blk, 0, stream>>>(bq + l * Hc, bk + l * Hc, bv + l * Hc, bqkv);

        ln_k<false><<<gLN, blk, 0, stream>>>(h, ln1g + l * Hc, ln1b + l * Hc, y, nullptr);
        gemm2_k<0, false><<<gQKV, blk, 0, stream>>>(y, wqkvt, bqkv, nullptr, nullptr, qkv, MR, QS, Hc);
        attn_k<<<gA, blk, 0, stream>>>(qkv, qkv + Hc, qkv + 2 * Hc, abias, ob);
        gemm2_k<0, true><<<gP, blk, 0, stream>>>(ob, wot, bo + l * Hc, h, h, nullptr, MR, Hc, Hc);
        ln_k<false><<<gLN, blk, 0, stream>>>(h, ln2g + l * Hc, ln2b + l * Hc, y, nullptr);
        gemm2_k<1, false><<<gF, blk, 0, stream>>>(y, w1t, b1 + l * FFc, nullptr, nullptr, fb, MR, FFc, Hc);
        gemm2_k<0, true><<<gP, blk, 0, stream>>>(fb, w2t, b2 + l * Hc, h, h, nullptr, MR, Hc, FFc);
    }
    ln_k<true><<<gLN, blk, 0, stream>>>(h, flng, flnb, nullptr, h);
}

// Round 3
// 1726.049 us; speedup vs baseline: 1.9837x; 1.0169x over previous
//
#include <hip/hip_runtime.h>
#include <math.h>

// ---------------- problem constants ----------------
constexpr int Lc = 4, Bc = 16, Sc = 512, Hc = 768, NHc = 12, FFc = 3072, Dc = 64;
constexpr int MR = Bc * Sc;            // 8192 token rows
constexpr int QS = 2304;               // fused QKV row stride
constexpr float SCALEc = 0.125f;       // D^-0.5

typedef __attribute__((ext_vector_type(8))) __bf16 bf16x8;
typedef __attribute__((ext_vector_type(4))) __bf16 bf16x4;
typedef __attribute__((ext_vector_type(4))) float  floatx4;

__device__ inline floatx4 mfma16(bf16x8 a, bf16x8 b, floatx4 c) {
    return __builtin_amdgcn_mfma_f32_16x16x32_bf16(a, b, c, 0, 0, 0);
}
__device__ inline float gelu_f(float x) {
    return 0.5f * x * (1.0f + erff(x * 0.70710678118654752f));
}
// async global->LDS, 16B per lane; LDS dest = wave-uniform base + lane*16
__device__ inline void ld16(const __bf16* g, __bf16* l) {
    __builtin_amdgcn_global_load_lds(
        (const __attribute__((address_space(1))) void*)g,
        (__attribute__((address_space(3))) void*)l, 16, 0, 0);
}

// ---------------- LayerNorm: one wave per row ----------
template<bool FINAL>
__global__ __launch_bounds__(256) void ln_k(
    const float* __restrict__ x, const float* __restrict__ g, const float* __restrict__ bt,
    __bf16* __restrict__ yb, float* __restrict__ yf)
{
    const int row  = blockIdx.x * 4 + (threadIdx.x >> 6);
    const int lane = threadIdx.x & 63;
    const int col  = lane * 12;
    const float* xr = x + (size_t)row * Hc + col;
    float v[12];
    *(float4*)(v + 0) = *(const float4*)(xr + 0);
    *(float4*)(v + 4) = *(const float4*)(xr + 4);
    *(float4*)(v + 8) = *(const float4*)(xr + 8);
    float s = 0.f, s2 = 0.f;
#pragma unroll
    for (int j = 0; j < 12; ++j) { s += v[j]; s2 += v[j] * v[j]; }
#pragma unroll
    for (int o = 32; o > 0; o >>= 1) { s += __shfl_xor(s, o); s2 += __shfl_xor(s2, o); }
    const float mean = s * (1.0f / Hc);
    const float inv  = rsqrtf(s2 * (1.0f / Hc) - mean * mean + 1e-5f);
    float gv[12], bv[12];
    *(float4*)(gv + 0) = *(const float4*)(g + col);
    *(float4*)(gv + 4) = *(const float4*)(g + col + 4);
    *(float4*)(gv + 8) = *(const float4*)(g + col + 8);
    *(float4*)(bv + 0) = *(const float4*)(bt + col);
    *(float4*)(bv + 4) = *(const float4*)(bt + col + 4);
    *(float4*)(bv + 8) = *(const float4*)(bt + col + 8);
    if (FINAL) {
        float o[12];
#pragma unroll
        for (int j = 0; j < 12; ++j) o[j] = (v[j] - mean) * inv * gv[j] + bv[j];
        float* yr = yf + (size_t)row * Hc + col;
        *(float4*)(yr + 0) = *(float4*)(o + 0);
        *(float4*)(yr + 4) = *(float4*)(o + 4);
        *(float4*)(yr + 8) = *(float4*)(o + 8);
    } else {
        __bf16 o[12];
#pragma unroll
        for (int j = 0; j < 12; ++j) o[j] = (__bf16)((v[j] - mean) * inv * gv[j] + bv[j]);
        __bf16* yr = yb + (size_t)row * Hc + col;
        *(bf16x4*)(yr + 0) = *(bf16x4*)(o + 0);
        *(bf16x4*)(yr + 4) = *(bf16x4*)(o + 4);
        *(bf16x4*)(yr + 8) = *(bf16x4*)(o + 8);
    }
}

// ---------------- weight transpose+convert: in fp32 [R][C] -> out bf16 [C][R] ---
__global__ __launch_bounds__(256) void transp_k(
    const float* __restrict__ in, __bf16* __restrict__ out, int R, int C)
{
    __shared__ float t[32][33];
    const int c0 = blockIdx.x * 32, r0 = blockIdx.y * 32;
    const int tx = threadIdx.x & 31, ty = threadIdx.x >> 5;   // 32 x 8
#pragma unroll
    for (int i = 0; i < 4; ++i)
        t[ty + i * 8][tx] = in[(size_t)(r0 + ty + i * 8) * C + c0 + tx];
    __syncthreads();
#pragma unroll
    for (int i = 0; i < 4; ++i)
        out[(size_t)(c0 + ty + i * 8) * R + r0 + tx] = (__bf16)t[tx][ty + i * 8];
}

__global__ void bias_cat_k(const float* __restrict__ a, const float* __restrict__ b,
                           const float* __restrict__ c, float* __restrict__ o)
{
    int i = threadIdx.x + blockIdx.x * 256;
    if (i < QS) o[i] = i < Hc ? a[i] : (i < 2 * Hc ? b[i - Hc] : c[i - 2 * Hc]);
}

// ---------------- GEMM 128x128 (4 waves): for wide-N gemms (QKV, FFN1) --------
template<int ACT, bool RESID>
__global__ __launch_bounds__(256) void gemm2_k(
    const __bf16* __restrict__ A, const __bf16* __restrict__ Bt,
    const float* __restrict__ bias, const float* __restrict__ resid,
    float* __restrict__ outF, __bf16* __restrict__ outB,
    int M, int N, int K)
{
    __shared__ alignas(16) __bf16 As[128 * 32];
    __shared__ alignas(16) __bf16 Bs[128 * 32];
    const int tid  = threadIdx.x;
    const int wave = tid >> 6, lane = tid & 63, lhi = lane >> 4, llo = lane & 15;
    const int wm = wave >> 1, wn = wave & 1;
    const int row0 = blockIdx.y * 128, col0 = blockIdx.x * 128;
    const int srow = lane >> 2;            // 0..15
    const int scol = (lane & 3) * 8;       // 0,8,16,24

    floatx4 acc[4][4];
#pragma unroll
    for (int i = 0; i < 4; ++i)
#pragma unroll
        for (int j = 0; j < 4; ++j) acc[i][j] = {0.f, 0.f, 0.f, 0.f};

    const __bf16* Ab = A  + (size_t)(row0 + wave * 16 + srow) * K + scol;
    const __bf16* Bb = Bt + (size_t)(col0 + wave * 16 + srow) * K + scol;

    for (int kt = 0; kt < K; kt += 32) {
#pragma unroll
        for (int t = 0; t < 2; ++t) {
            ld16(Ab + (size_t)(t * 64) * K + kt, As + (t * 64 + wave * 16) * 32);
            ld16(Bb + (size_t)(t * 64) * K + kt, Bs + (t * 64 + wave * 16) * 32);
        }
        __syncthreads();
        bf16x8 af[4], bfr[4];
#pragma unroll
        for (int i = 0; i < 4; ++i)
            af[i]  = *(const bf16x8*)(As + (wm * 64 + i * 16 + llo) * 32 + lhi * 8);
#pragma unroll
        for (int j = 0; j < 4; ++j)
            bfr[j] = *(const bf16x8*)(Bs + (wn * 64 + j * 16 + llo) * 32 + lhi * 8);
#pragma unroll
        for (int i = 0; i < 4; ++i)
#pragma unroll
            for (int j = 0; j < 4; ++j)
                acc[i][j] = mfma16(af[i], bfr[j], acc[i][j]);
        __syncthreads();
    }
#pragma unroll
    for (int i = 0; i < 4; ++i) {
#pragma unroll
        for (int j = 0; j < 4; ++j) {
            int colc = col0 + wn * 64 + j * 16 + llo;
            float bb = bias[colc];
#pragma unroll
            for (int r = 0; r < 4; ++r) {
                int rowc = row0 + wm * 64 + i * 16 + lhi * 4 + r;
                float vv = acc[i][j][r] + bb;
                if (ACT == 1) vv = gelu_f(vv);
                size_t idx = (size_t)rowc * N + colc;
                if (RESID) outF[idx] = resid[idx] + vv;
                else       outB[idx] = (__bf16)vv;
            }
        }
    }
}

// ---------------- GEMM 128x64 (2 waves): for N=768 resid gemms (O-proj, FFN2) ---
// 768 blocks -> 3/CU balanced (vs 384 -> 1.5/CU tail imbalance).
__global__ __launch_bounds__(128) void gemm3_k(
    const __bf16* __restrict__ A, const __bf16* __restrict__ Bt,
    const float* __restrict__ bias, const float* __restrict__ resid,
    float* __restrict__ outF, int M, int N, int K)
{
    __shared__ alignas(16) __bf16 As[128 * 32];
    __shared__ alignas(16) __bf16 Bs[64 * 32];
    const int tid  = threadIdx.x;
    const int wave = tid >> 6, lane = tid & 63, lhi = lane >> 4, llo = lane & 15;
    const int row0 = blockIdx.y * 128, col0 = blockIdx.x * 64;
    const int srow = lane >> 2;
    const int scol = (lane & 3) * 8;

    floatx4 acc[4][4];
#pragma unroll
    for (int i = 0; i < 4; ++i)
#pragma unroll
        for (int j = 0; j < 4; ++j) acc[i][j] = {0.f, 0.f, 0.f, 0.f};

    const __bf16* Ab = A  + (size_t)(row0 + wave * 64 + srow) * K + scol;  // wave w: rows w*64..
    const __bf16* Bb = Bt + (size_t)(col0 + wave * 32 + srow) * K + scol;  // wave w: cols w*32..

    for (int kt = 0; kt < K; kt += 32) {
#pragma unroll
        for (int t = 0; t < 4; ++t)
            ld16(Ab + (size_t)(t * 16) * K + kt, As + (wave * 64 + t * 16) * 32);
#pragma unroll
        for (int t = 0; t < 2; ++t)
            ld16(Bb + (size_t)(t * 16) * K + kt, Bs + (wave * 32 + t * 16) * 32);
        __syncthreads();
        bf16x8 af[4], bfr[4];
#pragma unroll
        for (int i = 0; i < 4; ++i)
            af[i]  = *(const bf16x8*)(As + (wave * 64 + i * 16 + llo) * 32 + lhi * 8);
#pragma unroll
        for (int j = 0; j < 4; ++j)
            bfr[j] = *(const bf16x8*)(Bs + (j * 16 + llo) * 32 + lhi * 8);
#pragma unroll
        for (int i = 0; i < 4; ++i)
#pragma unroll
            for (int j = 0; j < 4; ++j)
                acc[i][j] = mfma16(af[i], bfr[j], acc[i][j]);
        __syncthreads();
    }
#pragma unroll
    for (int i = 0; i < 4; ++i) {
#pragma unroll
        for (int j = 0; j < 4; ++j) {
            int colc = col0 + j * 16 + llo;
            float bb = bias[colc];
#pragma unroll
            for (int r = 0; r < 4; ++r) {
                int rowc = row0 + wave * 64 + i * 16 + lhi * 4 + r;
                size_t idx = (size_t)rowc * N + colc;
                outF[idx] = resid[idx] + acc[i][j][r] + bb;
            }
        }
    }
}

// ---------------- Flash attention ----------------
// grid: x = b*NH + h (192 = 24*8 -> same-(b,h) q-tiles land on one XCD
// under round-robin), y = q-tile. Vt row stride 66 breaks the 16-way
// bank alias of the transpose stores (288%32==0 -> 264%32==8).
__global__ __launch_bounds__(256) void attn_k(
    const __bf16* __restrict__ q, const __bf16* __restrict__ k,
    const __bf16* __restrict__ v, const float* __restrict__ bias,
    __bf16* __restrict__ o)
{
    __shared__ alignas(16) __bf16 Qs[64][72];
    __shared__ alignas(16) __bf16 Ks[64][72];
    __shared__ alignas(16) __bf16 Vt[64][66];   // [d][t], stride 66
    __shared__ alignas(16) __bf16 Ps[64][72];
    __shared__ float  Sf[64][68];
    __shared__ float  mrun[64], lrun[64], alf[64];

    const int hh = blockIdx.x % NHc, b = blockIdx.x / NHc, qt = blockIdx.y;
    const int tid = threadIdx.x, wave = tid >> 6, lane = tid & 63;
    const int lhi = lane >> 4, llo = lane & 15;
    const size_t base  = (size_t)b * Sc * QS + hh * Dc;   // qkv addressing
    const size_t obase = (size_t)b * Sc * Hc + hh * Dc;   // output addressing

#pragma unroll
    for (int c = 0; c < 2; ++c) {
        int id = tid + c * 256;
        int r = id >> 3, c8 = id & 7;
        *(bf16x8*)(&Qs[r][c8 * 8]) =
            *(const bf16x8*)(q + base + (size_t)(qt * 64 + r) * QS + c8 * 8);
    }
    if (tid < 64) { mrun[tid] = -1e30f; lrun[tid] = 0.f; }

    floatx4 acco[4];
#pragma unroll
    for (int j = 0; j < 4; ++j) acco[j] = {0.f, 0.f, 0.f, 0.f};

    const float* brow = bias + ((size_t)(b * NHc + hh) * Sc + qt * 64) * Sc;

    for (int kt = 0; kt < Sc; kt += 64) {
        __syncthreads();
#pragma unroll
        for (int c = 0; c < 2; ++c) {
            int id = tid + c * 256;
            int r = id >> 3, c8 = id & 7;
            *(bf16x8*)(&Ks[r][c8 * 8]) =
                *(const bf16x8*)(k + base + (size_t)(kt + r) * QS + c8 * 8);
            bf16x8 vv = *(const bf16x8*)(v + base + (size_t)(kt + r) * QS + c8 * 8);
#pragma unroll
            for (int jj = 0; jj < 8; ++jj) Vt[c8 * 8 + jj][r] = vv[jj];
        }
        __syncthreads();
        floatx4 accs[4];
#pragma unroll
        for (int j = 0; j < 4; ++j) accs[j] = {0.f, 0.f, 0.f, 0.f};
#pragma unroll
        for (int kk = 0; kk < 2; ++kk) {
            bf16x8 aq = *(const bf16x8*)(&Qs[wave * 16 + llo][kk * 32 + lhi * 8]);
#pragma unroll
            for (int nf = 0; nf < 4; ++nf) {
                bf16x8 bk2 = *(const bf16x8*)(&Ks[nf * 16 + llo][kk * 32 + lhi * 8]);
                accs[nf] = mfma16(aq, bk2, accs[nf]);
            }
        }
#pragma unroll
        for (int nf = 0; nf < 4; ++nf) {
#pragma unroll
            for (int r = 0; r < 4; ++r) {
                int lr = wave * 16 + lhi * 4 + r;
                float sv = accs[nf][r] * SCALEc + brow[(size_t)lr * Sc + kt + nf * 16 + llo];
                Sf[lr][nf * 16 + llo] = sv;
            }
        }
        __syncthreads();
        {
            int row = tid >> 2, seg = tid & 3;
            float sv[16]; float mx = -1e30f;
#pragma unroll
            for (int j2 = 0; j2 < 16; ++j2) { sv[j2] = Sf[row][seg * 16 + j2]; mx = fmaxf(mx, sv[j2]); }
            mx = fmaxf(mx, __shfl_xor(mx, 1));
            mx = fmaxf(mx, __shfl_xor(mx, 2));
            float mold = mrun[row];
            float mnew = fmaxf(mold, mx);
            float al = __expf(mold - mnew);
            float sum = 0.f;
#pragma unroll
            for (int j2 = 0; j2 < 16; ++j2) {
                float p = __expf(sv[j2] - mnew);
                sum += p;
                Ps[row][seg * 16 + j2] = (__bf16)p;
            }
            sum += __shfl_xor(sum, 1);
            sum += __shfl_xor(sum, 2);
            if (seg == 0) { mrun[row] = mnew; lrun[row] = lrun[row] * al + sum; alf[row] = al; }
        }
        __syncthreads();
#pragma unroll
        for (int nf = 0; nf < 4; ++nf)
#pragma unroll
            for (int r = 0; r < 4; ++r) acco[nf][r] *= alf[wave * 16 + lhi * 4 + r];
#pragma unroll
        for (int kk = 0; kk < 2; ++kk) {
            bf16x8 ap = *(const bf16x8*)(&Ps[wave * 16 + llo][kk * 32 + lhi * 8]);
#pragma unroll
            for (int nf = 0; nf < 4; ++nf) {
                bf16x8 bv2 = *(const bf16x8*)(&Vt[nf * 16 + llo][kk * 32 + lhi * 8]);
                acco[nf] = mfma16(ap, bv2, acco[nf]);
            }
        }
    }
#pragma unroll
    for (int nf = 0; nf < 4; ++nf) {
#pragma unroll
        for (int r = 0; r < 4; ++r) {
            int lr = wave * 16 + lhi * 4 + r;
            float oo = acco[nf][r] / lrun[lr];
            o[obase + (size_t)(qt * 64 + lr) * Hc + nf * 16 + llo] = (__bf16)oo;
        }
    }
}

// ---------------- orchestration ----------------
extern "C" void kernel_launch(void* const* d_in, const int* in_sizes, int n_in,
                              void* d_out, int out_size, void* d_ws, size_t ws_size,
                              hipStream_t stream)
{
    const float* x     = (const float*)d_in[0];
    const float* abias = (const float*)d_in[1];
    const float* ln1g  = (const float*)d_in[2];
    const float* ln1b  = (const float*)d_in[3];
    const float* wq    = (const float*)d_in[4];
    const float* bq    = (const float*)d_in[5];
    const float* wk    = (const float*)d_in[6];
    const float* bk    = (const float*)d_in[7];
    const float* wv    = (const float*)d_in[8];
    const float* bv    = (const float*)d_in[9];
    const float* wo    = (const float*)d_in[10];
    const float* bo    = (const float*)d_in[11];
    const float* ln2g  = (const float*)d_in[12];
    const float* ln2b  = (const float*)d_in[13];
    const float* w1    = (const float*)d_in[14];
    const float* b1    = (const float*)d_in[15];
    const float* w2    = (const float*)d_in[16];
    const float* b2    = (const float*)d_in[17];
    const float* flng  = (const float*)d_in[18];
    const float* flnb  = (const float*)d_in[19];

    float* h = (float*)d_out;                       // residual stream
    __bf16* y    = (__bf16*)d_ws;                   // [MR,768]
    __bf16* qkv  = y   + (size_t)MR * Hc;           // [MR,2304]
    __bf16* ob   = qkv + (size_t)MR * QS;           // [MR,768]
    __bf16* fb   = ob  + (size_t)MR * Hc;           // [MR,3072] FFN act
    __bf16* w1t  = fb  + (size_t)MR * FFc;          // [3072,768]
    __bf16* w2t  = w1t + (size_t)FFc * Hc;          // [768,3072]
    float*  bqkv = (float*)(w2t + (size_t)Hc * FFc);// [2304]
    // alias (dead before FFN act is written): QKV + O weights inside fb region
    __bf16* wqkvt = fb;                             // [2304,768]
    __bf16* wot   = fb + (size_t)QS * Hc;           // [768,768]

    hipMemcpyAsync(h, x, (size_t)MR * Hc * sizeof(float), hipMemcpyDeviceToDevice, stream);

    dim3 blk(256);
    dim3 gLN(MR / 4);
    dim3 gQKV(QS / 128, MR / 128);   // (18,64)
    dim3 gP64(Hc / 64, MR / 128);    // (12,64) = 768 blocks, 3/CU
    dim3 gF(FFc / 128, MR / 128);    // (24,64)
    dim3 gA(Bc * NHc, Sc / 64);      // (192,8): same-(b,h) blocks stride 192 -> one XCD
    dim3 gT_HH(Hc / 32, Hc / 32);
    dim3 gT_HF(FFc / 32, Hc / 32);
    dim3 gT_FH(Hc / 32, FFc / 32);

    for (int l = 0; l < Lc; ++l) {
        const float* wq_l = wq + (size_t)l * Hc * Hc;
        const float* wk_l = wk + (size_t)l * Hc * Hc;
        const float* wv_l = wv + (size_t)l * Hc * Hc;
        const float* wo_l = wo + (size_t)l * Hc * Hc;
        const float* w1_l = w1 + (size_t)l * Hc * FFc;
        const float* w2_l = w2 + (size_t)l * FFc * Hc;

        // weight prep (bf16, transposed to [N][K])
        transp_k<<<gT_HH, blk, 0, stream>>>(wq_l, wqkvt,                        Hc, Hc);
        transp_k<<<gT_HH, blk, 0, stream>>>(wk_l, wqkvt + (size_t)Hc * Hc,      Hc, Hc);
        transp_k<<<gT_HH, blk, 0, stream>>>(wv_l, wqkvt + (size_t)2 * Hc * Hc,  Hc, Hc);
        transp_k<<<gT_HH, blk, 0, stream>>>(wo_l, wot, Hc, Hc);
        transp_k<<<gT_HF, blk, 0, stream>>>(w1_l, w1t, Hc, FFc);
        transp_k<<<gT_FH, blk, 0, stream>>>(w2_l, w2t, FFc, Hc);
        bias_cat_k<<<dim3(9), blk, 0, stream>>>(bq + l * Hc, bk + l * Hc, bv + l * Hc, bqkv);

        ln_k<false><<<gLN, blk, 0, stream>>>(h, ln1g + l * Hc, ln1b + l * Hc, y, nullptr);
        gemm2_k<0, false><<<gQKV, blk, 0, stream>>>(y, wqkvt, bqkv, nullptr, nullptr, qkv, MR, QS, Hc);
        attn_k<<<gA, blk, 0, stream>>>(qkv, qkv + Hc, qkv + 2 * Hc, abias, ob);
        gemm3_k<<<gP64, dim3(128), 0, stream>>>(ob, wot, bo + l * Hc, h, h, MR, Hc, Hc);
        ln_k<false><<<gLN, blk, 0, stream>>>(h, ln2g + l * Hc, ln2b + l * Hc, y, nullptr);
        gemm2_k<1, false><<<gF, blk, 0, stream>>>(y, w1t, b1 + l * FFc, nullptr, nullptr, fb, MR, FFc, Hc);
        gemm3_k<<<gP64, dim3(128), 0, stream>>>(fb, w2t, b2 + l * Hc, h, h, MR, Hc, FFc);
    }
    ln_k<true><<<gLN, blk, 0, stream>>>(h, flng, flnb, nullptr, h);
}